// Round 3
// baseline (416.296 us; speedup 1.0000x reference)
//
#include <hip/hip_runtime.h>
#include <math.h>

// PointNetConv scatter-max, two-level binned:
//   out[i] = max over edges (src->i) of concat(x[src], pos[src]-pos[i]), 0 if none.
// x: [50000,128] f32, pos: [50000,3] f32, edge_index: [2,1600000] int32 (harness)
// out: [50000,131] f32
//
// Round-2 lesson (rocprof): random 4B global writes (csr scatter) cost a full
// ~64B HBM writeback each (101 MB WRITE_SIZE, 144 us) -- 8 non-coherent XCD L2s
// ping-pong shared lines. This version only ever writes global memory in
// coalesced runs; the fine max-reduction lives entirely in LDS.

#define N_NODES 50000
#define N_EDGES 1600000
#define NF      128
#define NOUT    131
#define NPB     64                       // nodes per coarse bucket
#define NB      ((N_NODES + NPB - 1) / NPB)   // 782 buckets
#define CHUNK   8192                     // edges per coarse_scatter block

// Order-preserving float->uint map; mapped 0 == NaN == "empty" sentinel.
__device__ __forceinline__ unsigned mapf(float f) {
    unsigned u = __float_as_uint(f);
    return (u & 0x80000000u) ? ~u : (u | 0x80000000u);
}
__device__ __forceinline__ float unmapf(unsigned u) {
    return (u & 0x80000000u) ? __uint_as_float(u & 0x7fffffffu)
                             : __uint_as_float(~u);
}

// ---------- A: coarse histogram (per-block LDS, one flush per bucket) ----------
__global__ __launch_bounds__(256) void coarse_hist(const int* __restrict__ ei,
                                                   int* __restrict__ gcount)
{
    __shared__ int h[NB];
    for (int i = threadIdx.x; i < NB; i += 256) h[i] = 0;
    __syncthreads();
    const int stride = gridDim.x * 256;
    for (int e = blockIdx.x * 256 + threadIdx.x; e < N_EDGES; e += stride)
        atomicAdd(&h[ei[N_EDGES + e] >> 6], 1);
    __syncthreads();
    for (int i = threadIdx.x; i < NB; i += 256)
        if (h[i]) atomicAdd(&gcount[i], h[i]);
}

// ---------- B: exclusive scan of 782 bucket counts (1 block, 1 wave) ----------
__global__ void coarse_scan(const int* __restrict__ gcount,
                            int* __restrict__ cstart,
                            int* __restrict__ gcursor)
{
    const int lane = threadIdx.x;  // launched with 64 threads
    int carry = 0;
    for (int base = 0; base <= NB; base += 64) {
        const int idx = base + lane;
        int v = (idx < NB) ? gcount[idx] : 0;
        int incl = v;
        #pragma unroll
        for (int off = 1; off < 64; off <<= 1) {
            int t = __shfl_up(incl, off, 64);
            if (lane >= off) incl += t;
        }
        if (idx <= NB) {
            const int excl = carry + incl - v;
            cstart[idx] = excl;
            if (idx < NB) gcursor[idx] = excl;
        }
        carry += __shfl(incl, 63, 64);
    }
}

// ---------- C: coarse scatter, LDS chunk-sort -> coalesced run appends ----------
// Packs (src | dloc<<16) into one u32: src < 50000 < 2^16, dloc < 64.
__global__ __launch_bounds__(256) void coarse_scatter(const int* __restrict__ ei,
                                                      int* __restrict__ gcursor,
                                                      unsigned* __restrict__ list)
{
    __shared__ unsigned sorted[CHUNK];       // 32 KB
    __shared__ unsigned short bos[CHUNK];    // 16 KB bucket-of-sorted
    __shared__ int hist[NB];
    __shared__ int lstart[NB + 1];
    __shared__ int cursor[NB];
    __shared__ int gbase[NB];

    const int tid = threadIdx.x;
    const int cbase = blockIdx.x * CHUNK;
    const int n = min(CHUNK, N_EDGES - cbase);

    for (int i = tid; i < NB; i += 256) hist[i] = 0;
    __syncthreads();

    for (int i = tid; i < n; i += 256)
        atomicAdd(&hist[ei[N_EDGES + cbase + i] >> 6], 1);
    __syncthreads();

    if (tid < 64) {  // one wave scans the 782 counts
        int carry = 0;
        for (int base = 0; base <= NB; base += 64) {
            const int idx = base + tid;
            int v = (idx < NB) ? hist[idx] : 0;
            int incl = v;
            #pragma unroll
            for (int off = 1; off < 64; off <<= 1) {
                int t = __shfl_up(incl, off, 64);
                if (tid >= off) incl += t;
            }
            if (idx <= NB) lstart[idx] = carry + incl - v;
            carry += __shfl(incl, 63, 64);
        }
    }
    __syncthreads();

    for (int i = tid; i < NB; i += 256) cursor[i] = lstart[i];
    __syncthreads();

    // LDS scatter: sorted[] ordered by bucket (ei re-read is L2-hot, coalesced)
    for (int i = tid; i < n; i += 256) {
        const int src = ei[cbase + i];
        const int d   = ei[N_EDGES + cbase + i];
        const int b   = d >> 6;
        const int p   = atomicAdd(&cursor[b], 1);
        sorted[p] = (unsigned)src | ((unsigned)(d & 63) << 16);
        bos[p] = (unsigned short)b;
    }
    __syncthreads();

    // claim global space per bucket (one atomic per non-empty bucket)
    for (int b = tid; b < NB; b += 256) {
        const int cnt = lstart[b + 1] - lstart[b];
        if (cnt > 0) gbase[b] = atomicAdd(&gcursor[b], cnt);
    }
    __syncthreads();

    // coalesced run writes (consecutive i in a bucket -> consecutive global pos)
    for (int i = tid; i < n; i += 256) {
        const int b = bos[i];
        list[gbase[b] + (i - lstart[b])] = sorted[i];
    }
}

// ---------- D: per-bucket gather-max into LDS accumulator ----------
__global__ __launch_bounds__(256) void bucket_gather(const float* __restrict__ x,
                                                     const float* __restrict__ pos,
                                                     const unsigned* __restrict__ list,
                                                     const int* __restrict__ cstart,
                                                     float* __restrict__ out)
{
    __shared__ unsigned acc[NPB * NOUT];   // 33.5 KB, layout == out rows
    __shared__ float posd[NPB * 3];

    const int tid = threadIdx.x;
    const int b = blockIdx.x;
    const int nodeBase = b << 6;
    const int nNodes = min(NPB, N_NODES - nodeBase);

    for (int i = tid; i < NPB * NOUT; i += 256) acc[i] = 0u;
    for (int i = tid; i < nNodes * 3; i += 256) posd[i] = pos[nodeBase * 3 + i];
    __syncthreads();

    const int lane = tid & 63;
    const int wid  = tid >> 6;
    const int beg = cstart[b];
    const int n   = cstart[b + 1] - beg;

    // wave-per-edge: 64 lanes read the 512B x-row coalesced (lane, lane+64),
    // LDS atomicMax stride-1 (2 lanes/bank = free).
    for (int base = wid * 64; base < n; base += 256) {
        const unsigned myp = (base + lane < n) ? list[beg + base + lane] : 0u;
        const int cnt = min(64, n - base);
        for (int j = 0; j < cnt; ++j) {
            const unsigned p = __shfl(myp, j, 64);
            const int src  = p & 0xFFFFu;
            const int dloc = p >> 16;
            const float* xr = x + src * NF;
            const float a0 = xr[lane];
            const float a1 = xr[lane + 64];
            unsigned* arow = acc + dloc * NOUT;
            atomicMax(&arow[lane],      mapf(a0));
            atomicMax(&arow[lane + 64], mapf(a1));
            if (lane < 3) {
                const float d = pos[src * 3 + lane] - posd[dloc * 3 + lane];
                atomicMax(&arow[NF + lane], mapf(d));
            }
        }
    }
    __syncthreads();

    const int total = nNodes * NOUT;
    for (int i = tid; i < total; i += 256) {
        const unsigned u = acc[i];
        out[nodeBase * NOUT + i] = (u == 0u) ? 0.0f : unmapf(u);  // empty -> 0 (PyG)
    }
}

// ---------- fallback (round-1 atomic path, zero ws) ----------
__global__ void edge_scatter_max(const float* __restrict__ x,
                                 const float* __restrict__ pos,
                                 const int* __restrict__ ei,
                                 unsigned* __restrict__ outu)
{
    const int lane = threadIdx.x & 63;
    const long long wavesPerBlock = blockDim.x >> 6;
    long long gwave = (long long)blockIdx.x * wavesPerBlock + (threadIdx.x >> 6);
    const long long nwaves = (long long)gridDim.x * wavesPerBlock;
    for (long long e = gwave; e < N_EDGES; e += nwaves) {
        const int src = ei[e];
        const int dst = ei[N_EDGES + e];
        const float2 xv = *(const float2*)(&x[(long long)src * NF + lane * 2]);
        unsigned* o = outu + (long long)dst * NOUT;
        atomicMax(&o[lane * 2],     mapf(xv.x));
        atomicMax(&o[lane * 2 + 1], mapf(xv.y));
        if (lane < 3) {
            const float d = pos[src * 3 + lane] - pos[dst * 3 + lane];
            atomicMax(&o[NF + lane], mapf(d));
        }
    }
}

__global__ void finalize_kernel(unsigned* __restrict__ buf)
{
    const long long total = (long long)N_NODES * NOUT;
    for (long long i = (long long)blockIdx.x * blockDim.x + threadIdx.x;
         i < total; i += (long long)gridDim.x * blockDim.x) {
        const unsigned u = buf[i];
        ((float*)buf)[i] = (u == 0u) ? 0.0f : unmapf(u);
    }
}

// ---------- launch ----------
extern "C" void kernel_launch(void* const* d_in, const int* in_sizes, int n_in,
                              void* d_out, int out_size, void* d_ws, size_t ws_size,
                              hipStream_t stream)
{
    const float* x   = (const float*)d_in[0];
    const float* pos = (const float*)d_in[1];
    const int*   ei  = (const int*)d_in[2];
    float* out = (float*)d_out;

    // ws: gcount[NB], cstart[NB+1], gcursor[NB], list[N_EDGES]  (~6.42 MB)
    const size_t gcount_off = 0;
    const size_t cstart_off = (gcount_off + (size_t)NB * 4 + 255) & ~(size_t)255;
    const size_t gcur_off   = (cstart_off + (size_t)(NB + 1) * 4 + 255) & ~(size_t)255;
    const size_t list_off   = (gcur_off + (size_t)NB * 4 + 255) & ~(size_t)255;
    const size_t ws_needed  = list_off + (size_t)N_EDGES * 4;

    if (ws_size < ws_needed) {
        unsigned* outu = (unsigned*)d_out;
        hipMemsetAsync(d_out, 0, (size_t)N_NODES * NOUT * sizeof(float), stream);
        edge_scatter_max<<<(N_EDGES + 3) / 4, 256, 0, stream>>>(x, pos, ei, outu);
        const long long total = (long long)N_NODES * NOUT;
        finalize_kernel<<<(int)((total + 255) / 256), 256, 0, stream>>>(outu);
        return;
    }

    int* gcount      = (int*)((char*)d_ws + gcount_off);
    int* cstart      = (int*)((char*)d_ws + cstart_off);
    int* gcursor     = (int*)((char*)d_ws + gcur_off);
    unsigned* list   = (unsigned*)((char*)d_ws + list_off);

    hipMemsetAsync(gcount, 0, (size_t)NB * 4, stream);

    coarse_hist<<<256, 256, 0, stream>>>(ei, gcount);
    coarse_scan<<<1, 64, 0, stream>>>(gcount, cstart, gcursor);
    coarse_scatter<<<(N_EDGES + CHUNK - 1) / CHUNK, 256, 0, stream>>>(ei, gcursor, list);
    bucket_gather<<<NB, 256, 0, stream>>>(x, pos, list, cstart, out);
}

// Round 4
// 177.824 us; speedup vs baseline: 2.3411x; 2.3411x over previous
//
#include <hip/hip_runtime.h>
#include <math.h>

// PointNetConv scatter-max, two-level binned + in-LDS counting sort + register gather:
//   out[i] = max over edges (src->i) of concat(x[src], pos[src]-pos[i]), 0 if none.
// x: [50000,128] f32, pos: [50000,3] f32, edge_index: [2,1600000] int32 (harness layout)
// out: [50000,131] f32
//
// Round-2 lesson: random 4B global writes cost a full HBM line each (101 MB writeback).
// Round-3 lesson: LDS-atomic accumulator + serial per-edge shfl loop + 32% occupancy
//   made the gather 2x slower than round-2's register gather. This round: coarse
//   binning (coalesced writes only) -> per-half-bucket LDS counting sort -> wave-per-
//   node REGISTER max with 4x-unrolled float2 row loads.

#define N_NODES 50000
#define N_EDGES 1600000
#define NF      128
#define NOUT    131
#define NPB     64                            // nodes per coarse bucket
#define NB      ((N_NODES + NPB - 1) / NPB)   // 782 buckets
#define CHUNK   8192                          // edges per coarse_scatter block
#define SCAP    4096                          // slist capacity in half_gather (chunked)

// ---------- A: coarse histogram (per-block LDS, one flush per bucket) ----------
__global__ __launch_bounds__(256) void coarse_hist(const int* __restrict__ ei,
                                                   int* __restrict__ gcount)
{
    __shared__ int h[NB];
    for (int i = threadIdx.x; i < NB; i += 256) h[i] = 0;
    __syncthreads();
    const int stride = gridDim.x * 256;
    for (int e = blockIdx.x * 256 + threadIdx.x; e < N_EDGES; e += stride)
        atomicAdd(&h[ei[N_EDGES + e] >> 6], 1);
    __syncthreads();
    for (int i = threadIdx.x; i < NB; i += 256)
        if (h[i]) atomicAdd(&gcount[i], h[i]);
}

// ---------- B: exclusive scan of 782 bucket counts (1 block, 1 wave) ----------
__global__ void coarse_scan(const int* __restrict__ gcount,
                            int* __restrict__ cstart,
                            int* __restrict__ gcursor)
{
    const int lane = threadIdx.x;  // 64 threads
    int carry = 0;
    for (int base = 0; base <= NB; base += 64) {
        const int idx = base + lane;
        int v = (idx < NB) ? gcount[idx] : 0;
        int incl = v;
        #pragma unroll
        for (int off = 1; off < 64; off <<= 1) {
            int t = __shfl_up(incl, off, 64);
            if (lane >= off) incl += t;
        }
        if (idx <= NB) {
            const int excl = carry + incl - v;
            cstart[idx] = excl;
            if (idx < NB) gcursor[idx] = excl;
        }
        carry += __shfl(incl, 63, 64);
    }
}

// ---------- C: coarse scatter, LDS chunk-sort -> coalesced run appends ----------
// Packs (src | dloc<<16): src < 50000 < 2^16, dloc < 64.
__global__ __launch_bounds__(256) void coarse_scatter(const int* __restrict__ ei,
                                                      int* __restrict__ gcursor,
                                                      unsigned* __restrict__ list)
{
    __shared__ unsigned sorted[CHUNK];       // 32 KB
    __shared__ unsigned short bos[CHUNK];    // 16 KB
    __shared__ int hist[NB];
    __shared__ int lstart[NB + 1];
    __shared__ int cursor[NB];
    __shared__ int gbase[NB];

    const int tid = threadIdx.x;
    const int cbase = blockIdx.x * CHUNK;
    const int n = min(CHUNK, N_EDGES - cbase);

    for (int i = tid; i < NB; i += 256) hist[i] = 0;
    __syncthreads();

    for (int i = tid; i < n; i += 256)
        atomicAdd(&hist[ei[N_EDGES + cbase + i] >> 6], 1);
    __syncthreads();

    if (tid < 64) {
        int carry = 0;
        for (int base = 0; base <= NB; base += 64) {
            const int idx = base + tid;
            int v = (idx < NB) ? hist[idx] : 0;
            int incl = v;
            #pragma unroll
            for (int off = 1; off < 64; off <<= 1) {
                int t = __shfl_up(incl, off, 64);
                if (tid >= off) incl += t;
            }
            if (idx <= NB) lstart[idx] = carry + incl - v;
            carry += __shfl(incl, 63, 64);
        }
    }
    __syncthreads();

    for (int i = tid; i < NB; i += 256) cursor[i] = lstart[i];
    __syncthreads();

    for (int i = tid; i < n; i += 256) {
        const int src = ei[cbase + i];
        const int d   = ei[N_EDGES + cbase + i];
        const int b   = d >> 6;
        const int p   = atomicAdd(&cursor[b], 1);
        sorted[p] = (unsigned)src | ((unsigned)(d & 63) << 16);
        bos[p] = (unsigned short)b;
    }
    __syncthreads();

    for (int b = tid; b < NB; b += 256) {
        const int cnt = lstart[b + 1] - lstart[b];
        if (cnt > 0) gbase[b] = atomicAdd(&gcursor[b], cnt);
    }
    __syncthreads();

    for (int i = tid; i < n; i += 256) {
        const int b = bos[i];
        list[gbase[b] + (i - lstart[b])] = sorted[i];
    }
}

// ---------- D: half-bucket counting sort + register gather ----------
// Block owns 32 nodes (half of coarse bucket blockIdx.x>>1). Counting-sorts its
// half's packed entries into slist (LDS), then wave w register-gathers nodes
// w*4 .. w*4+3 with 4x-unrolled float2 row loads. Output written exactly once.
__global__ __launch_bounds__(512) void half_gather(const float* __restrict__ x,
                                                   const float* __restrict__ pos,
                                                   const unsigned* __restrict__ list,
                                                   const int* __restrict__ cstart,
                                                   float* __restrict__ out)
{
    __shared__ unsigned slist[SCAP];   // 16 KB: src ids, sorted by local dst
    __shared__ int cnt[32];
    __shared__ int sstart[33];
    __shared__ int scur[32];

    const int tid  = threadIdx.x;
    const int lane = tid & 63;
    const int wid  = tid >> 6;               // 8 waves
    const int b    = blockIdx.x >> 1;        // coarse bucket
    const unsigned half = blockIdx.x & 1;    // which 32-node half
    const int nodeBase = blockIdx.x * 32;

    const int beg = cstart[b];
    const int n   = cstart[b + 1] - beg;

    float accx[4], accy[4], paccj[4], posi[4];
    #pragma unroll
    for (int k = 0; k < 4; ++k) {
        accx[k] = -INFINITY; accy[k] = -INFINITY; paccj[k] = -INFINITY;
        const int node = nodeBase + wid * 4 + k;
        posi[k] = (lane < 3 && node < N_NODES) ? pos[node * 3 + lane] : 0.f;
    }

    for (int cb = 0; cb < n; cb += SCAP) {
        const int m = min(SCAP, n - cb);
        __syncthreads();                    // protect slist from previous chunk's readers
        if (tid < 32) cnt[tid] = 0;
        __syncthreads();

        for (int i = tid; i < m; i += 512) {
            const unsigned dl = list[beg + cb + i] >> 16;
            if ((dl >> 5) == half) atomicAdd(&cnt[dl & 31], 1);
        }
        __syncthreads();

        if (tid < 32) {                     // 32-lane exclusive scan
            const int v = cnt[tid];
            int incl = v;
            #pragma unroll
            for (int off = 1; off < 32; off <<= 1) {
                int t = __shfl_up(incl, off, 64);
                if (tid >= off) incl += t;
            }
            sstart[tid] = incl - v;
            scur[tid]   = incl - v;
            if (tid == 31) sstart[32] = incl;
        }
        __syncthreads();

        for (int i = tid; i < m; i += 512) {
            const unsigned e = list[beg + cb + i];
            const unsigned dl = e >> 16;
            if ((dl >> 5) == half) {
                const int p = atomicAdd(&scur[dl & 31], 1);
                slist[p] = e & 0xFFFFu;
            }
        }
        __syncthreads();

        // register gather: wave handles 4 nodes, 4x-unrolled float2 row loads
        #pragma unroll
        for (int k = 0; k < 4; ++k) {
            const int dl = wid * 4 + k;
            const int re = sstart[dl + 1];
            int i = sstart[dl];
            for (; i + 4 <= re; i += 4) {
                const int s0 = slist[i], s1 = slist[i + 1];
                const int s2 = slist[i + 2], s3 = slist[i + 3];
                const float2 a0 = *(const float2*)(x + s0 * NF + lane * 2);
                const float2 a1 = *(const float2*)(x + s1 * NF + lane * 2);
                const float2 a2 = *(const float2*)(x + s2 * NF + lane * 2);
                const float2 a3 = *(const float2*)(x + s3 * NF + lane * 2);
                accx[k] = fmaxf(accx[k], fmaxf(fmaxf(a0.x, a1.x), fmaxf(a2.x, a3.x)));
                accy[k] = fmaxf(accy[k], fmaxf(fmaxf(a0.y, a1.y), fmaxf(a2.y, a3.y)));
                if (lane < 3) {
                    const float p0 = pos[s0 * 3 + lane], p1 = pos[s1 * 3 + lane];
                    const float p2 = pos[s2 * 3 + lane], p3 = pos[s3 * 3 + lane];
                    paccj[k] = fmaxf(paccj[k], fmaxf(fmaxf(p0, p1), fmaxf(p2, p3)));
                }
            }
            for (; i < re; ++i) {
                const int s0 = slist[i];
                const float2 a0 = *(const float2*)(x + s0 * NF + lane * 2);
                accx[k] = fmaxf(accx[k], a0.x);
                accy[k] = fmaxf(accy[k], a0.y);
                if (lane < 3) paccj[k] = fmaxf(paccj[k], pos[s0 * 3 + lane]);
            }
        }
    }

    // write out: max(pos_j - pos_i) == max(pos_j) - pos_i (monotone, exact);
    // acc == -inf  <=>  empty segment -> PyG zero-fill.
    #pragma unroll
    for (int k = 0; k < 4; ++k) {
        const int node = nodeBase + wid * 4 + k;
        if (node < N_NODES) {
            float* orow = out + (long long)node * NOUT;
            orow[lane * 2]     = (accx[k] == -INFINITY) ? 0.f : accx[k];
            orow[lane * 2 + 1] = (accy[k] == -INFINITY) ? 0.f : accy[k];
            if (lane < 3)
                orow[NF + lane] = (paccj[k] == -INFINITY) ? 0.f : (paccj[k] - posi[k]);
        }
    }
}

// ---------- fallback (round-1 atomic path, zero ws) ----------
__device__ __forceinline__ unsigned mapf(float f) {
    unsigned u = __float_as_uint(f);
    return (u & 0x80000000u) ? ~u : (u | 0x80000000u);
}
__device__ __forceinline__ float unmapf(unsigned u) {
    return (u & 0x80000000u) ? __uint_as_float(u & 0x7fffffffu)
                             : __uint_as_float(~u);
}

__global__ void edge_scatter_max(const float* __restrict__ x,
                                 const float* __restrict__ pos,
                                 const int* __restrict__ ei,
                                 unsigned* __restrict__ outu)
{
    const int lane = threadIdx.x & 63;
    const long long wavesPerBlock = blockDim.x >> 6;
    long long gwave = (long long)blockIdx.x * wavesPerBlock + (threadIdx.x >> 6);
    const long long nwaves = (long long)gridDim.x * wavesPerBlock;
    for (long long e = gwave; e < N_EDGES; e += nwaves) {
        const int src = ei[e];
        const int dst = ei[N_EDGES + e];
        const float2 xv = *(const float2*)(&x[(long long)src * NF + lane * 2]);
        unsigned* o = outu + (long long)dst * NOUT;
        atomicMax(&o[lane * 2],     mapf(xv.x));
        atomicMax(&o[lane * 2 + 1], mapf(xv.y));
        if (lane < 3) {
            const float d = pos[src * 3 + lane] - pos[dst * 3 + lane];
            atomicMax(&o[NF + lane], mapf(d));
        }
    }
}

__global__ void finalize_kernel(unsigned* __restrict__ buf)
{
    const long long total = (long long)N_NODES * NOUT;
    for (long long i = (long long)blockIdx.x * blockDim.x + threadIdx.x;
         i < total; i += (long long)gridDim.x * blockDim.x) {
        const unsigned u = buf[i];
        ((float*)buf)[i] = (u == 0u) ? 0.0f : unmapf(u);
    }
}

// ---------- launch ----------
extern "C" void kernel_launch(void* const* d_in, const int* in_sizes, int n_in,
                              void* d_out, int out_size, void* d_ws, size_t ws_size,
                              hipStream_t stream)
{
    const float* x   = (const float*)d_in[0];
    const float* pos = (const float*)d_in[1];
    const int*   ei  = (const int*)d_in[2];
    float* out = (float*)d_out;

    // ws: gcount[NB], cstart[NB+1], gcursor[NB], list[N_EDGES]  (~6.42 MB)
    const size_t gcount_off = 0;
    const size_t cstart_off = (gcount_off + (size_t)NB * 4 + 255) & ~(size_t)255;
    const size_t gcur_off   = (cstart_off + (size_t)(NB + 1) * 4 + 255) & ~(size_t)255;
    const size_t list_off   = (gcur_off + (size_t)NB * 4 + 255) & ~(size_t)255;
    const size_t ws_needed  = list_off + (size_t)N_EDGES * 4;

    if (ws_size < ws_needed) {
        unsigned* outu = (unsigned*)d_out;
        hipMemsetAsync(d_out, 0, (size_t)N_NODES * NOUT * sizeof(float), stream);
        edge_scatter_max<<<(N_EDGES + 3) / 4, 256, 0, stream>>>(x, pos, ei, outu);
        const long long total = (long long)N_NODES * NOUT;
        finalize_kernel<<<(int)((total + 255) / 256), 256, 0, stream>>>(outu);
        return;
    }

    int* gcount      = (int*)((char*)d_ws + gcount_off);
    int* cstart      = (int*)((char*)d_ws + cstart_off);
    int* gcursor     = (int*)((char*)d_ws + gcur_off);
    unsigned* list   = (unsigned*)((char*)d_ws + list_off);

    hipMemsetAsync(gcount, 0, (size_t)NB * 4, stream);

    coarse_hist<<<256, 256, 0, stream>>>(ei, gcount);
    coarse_scan<<<1, 64, 0, stream>>>(gcount, cstart, gcursor);
    coarse_scatter<<<(N_EDGES + CHUNK - 1) / CHUNK, 256, 0, stream>>>(ei, gcursor, list);
    half_gather<<<2 * NB, 512, 0, stream>>>(x, pos, list, cstart, out);
}

// Round 5
// 175.322 us; speedup vs baseline: 2.3745x; 1.0143x over previous
//
#include <hip/hip_runtime.h>
#include <math.h>

// PointNetConv scatter-max, two-level binned + in-LDS counting sort + register gather:
//   out[i] = max over edges (src->i) of concat(x[src], pos[src]-pos[i]), 0 if none.
// x: [50000,128] f32, pos: [50000,3] f32, edge_index: [2,1600000] int32 (harness layout)
// out: [50000,131] f32
//
// Round-2 lesson: random 4B global writes cost a full HBM line each.
// Round-3 lesson: LDS-atomic accumulate + serial shfl loop + low occupancy = 2x slower
//   than register gather.
// Round-4 lesson (rocprof): gather is latency-bound (VALUBusy 30%, occ 51%, neither
//   L2 nor LLC saturated). This round: float4 loads with 32 lanes/row -> 2 edges per
//   load instruction, 8 edges in flight per wave iteration.

#define N_NODES 50000
#define N_EDGES 1600000
#define NF      128
#define NOUT    131
#define NPB     64                            // nodes per coarse bucket
#define NB      ((N_NODES + NPB - 1) / NPB)   // 782 buckets
#define CHUNK   8192                          // edges per coarse_scatter block
#define SCAP    4096                          // slist capacity in half_gather (chunked)

// ---------- A: coarse histogram (per-block LDS, one flush per bucket) ----------
__global__ __launch_bounds__(256) void coarse_hist(const int* __restrict__ ei,
                                                   int* __restrict__ gcount)
{
    __shared__ int h[NB];
    for (int i = threadIdx.x; i < NB; i += 256) h[i] = 0;
    __syncthreads();
    const int stride = gridDim.x * 256;
    for (int e = blockIdx.x * 256 + threadIdx.x; e < N_EDGES; e += stride)
        atomicAdd(&h[ei[N_EDGES + e] >> 6], 1);
    __syncthreads();
    for (int i = threadIdx.x; i < NB; i += 256)
        if (h[i]) atomicAdd(&gcount[i], h[i]);
}

// ---------- B: exclusive scan of 782 bucket counts (1 block, 1 wave) ----------
__global__ void coarse_scan(const int* __restrict__ gcount,
                            int* __restrict__ cstart,
                            int* __restrict__ gcursor)
{
    const int lane = threadIdx.x;  // 64 threads
    int carry = 0;
    for (int base = 0; base <= NB; base += 64) {
        const int idx = base + lane;
        int v = (idx < NB) ? gcount[idx] : 0;
        int incl = v;
        #pragma unroll
        for (int off = 1; off < 64; off <<= 1) {
            int t = __shfl_up(incl, off, 64);
            if (lane >= off) incl += t;
        }
        if (idx <= NB) {
            const int excl = carry + incl - v;
            cstart[idx] = excl;
            if (idx < NB) gcursor[idx] = excl;
        }
        carry += __shfl(incl, 63, 64);
    }
}

// ---------- C: coarse scatter, LDS chunk-sort -> coalesced run appends ----------
// Packs (src | dloc<<16): src < 50000 < 2^16, dloc < 64.
__global__ __launch_bounds__(256) void coarse_scatter(const int* __restrict__ ei,
                                                      int* __restrict__ gcursor,
                                                      unsigned* __restrict__ list)
{
    __shared__ unsigned sorted[CHUNK];       // 32 KB
    __shared__ unsigned short bos[CHUNK];    // 16 KB
    __shared__ int hist[NB];
    __shared__ int lstart[NB + 1];
    __shared__ int cursor[NB];
    __shared__ int gbase[NB];

    const int tid = threadIdx.x;
    const int cbase = blockIdx.x * CHUNK;
    const int n = min(CHUNK, N_EDGES - cbase);

    for (int i = tid; i < NB; i += 256) hist[i] = 0;
    __syncthreads();

    for (int i = tid; i < n; i += 256)
        atomicAdd(&hist[ei[N_EDGES + cbase + i] >> 6], 1);
    __syncthreads();

    if (tid < 64) {
        int carry = 0;
        for (int base = 0; base <= NB; base += 64) {
            const int idx = base + tid;
            int v = (idx < NB) ? hist[idx] : 0;
            int incl = v;
            #pragma unroll
            for (int off = 1; off < 64; off <<= 1) {
                int t = __shfl_up(incl, off, 64);
                if (tid >= off) incl += t;
            }
            if (idx <= NB) lstart[idx] = carry + incl - v;
            carry += __shfl(incl, 63, 64);
        }
    }
    __syncthreads();

    for (int i = tid; i < NB; i += 256) cursor[i] = lstart[i];
    __syncthreads();

    for (int i = tid; i < n; i += 256) {
        const int src = ei[cbase + i];
        const int d   = ei[N_EDGES + cbase + i];
        const int b   = d >> 6;
        const int p   = atomicAdd(&cursor[b], 1);
        sorted[p] = (unsigned)src | ((unsigned)(d & 63) << 16);
        bos[p] = (unsigned short)b;
    }
    __syncthreads();

    for (int b = tid; b < NB; b += 256) {
        const int cnt = lstart[b + 1] - lstart[b];
        if (cnt > 0) gbase[b] = atomicAdd(&gcursor[b], cnt);
    }
    __syncthreads();

    for (int i = tid; i < n; i += 256) {
        const int b = bos[i];
        list[gbase[b] + (i - lstart[b])] = sorted[i];
    }
}

// ---------- D: half-bucket counting sort + paired float4 register gather ----------
// Block owns 32 nodes (half of coarse bucket blockIdx.x>>1). Counting-sorts its
// half's packed entries into slist (LDS). Gather: lanes split as (h = lane>>5,
// c = lane&31): the wave processes 2 edges per float4 load instruction (32 lanes
// cover one 512B x-row), 4 pairs (8 edges) in flight per iteration. Cross-half
// merge via shfl_xor(32) at the epilogue; output written exactly once.
__global__ __launch_bounds__(512) void half_gather(const float* __restrict__ x,
                                                   const float* __restrict__ pos,
                                                   const unsigned* __restrict__ list,
                                                   const int* __restrict__ cstart,
                                                   float* __restrict__ out)
{
    __shared__ unsigned slist[SCAP];   // 16 KB: src ids, sorted by local dst
    __shared__ int cnt[32];
    __shared__ int sstart[33];
    __shared__ int scur[32];

    const int tid  = threadIdx.x;
    const int lane = tid & 63;
    const int c    = lane & 31;              // feature-quad index
    const int h    = lane >> 5;              // which edge of the pair
    const int wid  = tid >> 6;               // 8 waves
    const int b    = blockIdx.x >> 1;        // coarse bucket
    const unsigned half = blockIdx.x & 1;    // which 32-node half
    const int nodeBase = blockIdx.x * 32;

    const int beg = cstart[b];
    const int n   = cstart[b + 1] - beg;

    float4 acc[4];
    float pacc[4];
    #pragma unroll
    for (int k = 0; k < 4; ++k) {
        acc[k] = make_float4(-INFINITY, -INFINITY, -INFINITY, -INFINITY);
        pacc[k] = -INFINITY;
    }

    for (int cb = 0; cb < n; cb += SCAP) {
        const int m = min(SCAP, n - cb);
        __syncthreads();                    // protect slist from previous chunk's readers
        if (tid < 32) cnt[tid] = 0;
        __syncthreads();

        for (int i = tid; i < m; i += 512) {
            const unsigned dl = list[beg + cb + i] >> 16;
            if ((dl >> 5) == half) atomicAdd(&cnt[dl & 31], 1);
        }
        __syncthreads();

        if (tid < 32) {                     // 32-lane exclusive scan
            const int v = cnt[tid];
            int incl = v;
            #pragma unroll
            for (int off = 1; off < 32; off <<= 1) {
                int t = __shfl_up(incl, off, 64);
                if (tid >= off) incl += t;
            }
            sstart[tid] = incl - v;
            scur[tid]   = incl - v;
            if (tid == 31) sstart[32] = incl;
        }
        __syncthreads();

        for (int i = tid; i < m; i += 512) {
            const unsigned e = list[beg + cb + i];
            const unsigned dl = e >> 16;
            if ((dl >> 5) == half) {
                const int p = atomicAdd(&scur[dl & 31], 1);
                slist[p] = e & 0xFFFFu;
            }
        }
        __syncthreads();

        #pragma unroll
        for (int k = 0; k < 4; ++k) {
            const int dl = wid * 4 + k;
            const int rb = sstart[dl];
            const int re = sstart[dl + 1];
            const int npairs = (re - rb + 1) >> 1;   // 0 if empty
            int p = 0;
            for (; p + 4 <= npairs; p += 4) {        // 8 edges in flight
                const int s0 = slist[min(rb + 2 * (p + 0) + h, re - 1)];
                const int s1 = slist[min(rb + 2 * (p + 1) + h, re - 1)];
                const int s2 = slist[min(rb + 2 * (p + 2) + h, re - 1)];
                const int s3 = slist[min(rb + 2 * (p + 3) + h, re - 1)];
                const float4 a0 = *(const float4*)(x + s0 * NF + c * 4);
                const float4 a1 = *(const float4*)(x + s1 * NF + c * 4);
                const float4 a2 = *(const float4*)(x + s2 * NF + c * 4);
                const float4 a3 = *(const float4*)(x + s3 * NF + c * 4);
                if (c < 3) {
                    const float q0 = pos[s0 * 3 + c], q1 = pos[s1 * 3 + c];
                    const float q2 = pos[s2 * 3 + c], q3 = pos[s3 * 3 + c];
                    pacc[k] = fmaxf(pacc[k], fmaxf(fmaxf(q0, q1), fmaxf(q2, q3)));
                }
                acc[k].x = fmaxf(acc[k].x, fmaxf(fmaxf(a0.x, a1.x), fmaxf(a2.x, a3.x)));
                acc[k].y = fmaxf(acc[k].y, fmaxf(fmaxf(a0.y, a1.y), fmaxf(a2.y, a3.y)));
                acc[k].z = fmaxf(acc[k].z, fmaxf(fmaxf(a0.z, a1.z), fmaxf(a2.z, a3.z)));
                acc[k].w = fmaxf(acc[k].w, fmaxf(fmaxf(a0.w, a1.w), fmaxf(a2.w, a3.w)));
            }
            for (; p < npairs; ++p) {
                const int s0 = slist[min(rb + 2 * p + h, re - 1)];
                const float4 a0 = *(const float4*)(x + s0 * NF + c * 4);
                if (c < 3) pacc[k] = fmaxf(pacc[k], pos[s0 * 3 + c]);
                acc[k].x = fmaxf(acc[k].x, a0.x);
                acc[k].y = fmaxf(acc[k].y, a0.y);
                acc[k].z = fmaxf(acc[k].z, a0.z);
                acc[k].w = fmaxf(acc[k].w, a0.w);
            }
        }
    }

    // cross-half merge; write out. max(pos_j - pos_i) == max(pos_j) - pos_i (exact);
    // acc == -inf <=> empty segment -> PyG zero-fill.
    #pragma unroll
    for (int k = 0; k < 4; ++k) {
        acc[k].x = fmaxf(acc[k].x, __shfl_xor(acc[k].x, 32, 64));
        acc[k].y = fmaxf(acc[k].y, __shfl_xor(acc[k].y, 32, 64));
        acc[k].z = fmaxf(acc[k].z, __shfl_xor(acc[k].z, 32, 64));
        acc[k].w = fmaxf(acc[k].w, __shfl_xor(acc[k].w, 32, 64));
        pacc[k]  = fmaxf(pacc[k],  __shfl_xor(pacc[k],  32, 64));
        const int node = nodeBase + wid * 4 + k;
        if (node < N_NODES && h == 0) {
            float* orow = out + (long long)node * NOUT;
            orow[c * 4 + 0] = (acc[k].x == -INFINITY) ? 0.f : acc[k].x;
            orow[c * 4 + 1] = (acc[k].y == -INFINITY) ? 0.f : acc[k].y;
            orow[c * 4 + 2] = (acc[k].z == -INFINITY) ? 0.f : acc[k].z;
            orow[c * 4 + 3] = (acc[k].w == -INFINITY) ? 0.f : acc[k].w;
            if (c < 3)
                orow[NF + c] = (pacc[k] == -INFINITY) ? 0.f
                                                      : (pacc[k] - pos[node * 3 + c]);
        }
    }
}

// ---------- fallback (round-1 atomic path, zero ws) ----------
__device__ __forceinline__ unsigned mapf(float f) {
    unsigned u = __float_as_uint(f);
    return (u & 0x80000000u) ? ~u : (u | 0x80000000u);
}
__device__ __forceinline__ float unmapf(unsigned u) {
    return (u & 0x80000000u) ? __uint_as_float(u & 0x7fffffffu)
                             : __uint_as_float(~u);
}

__global__ void edge_scatter_max(const float* __restrict__ x,
                                 const float* __restrict__ pos,
                                 const int* __restrict__ ei,
                                 unsigned* __restrict__ outu)
{
    const int lane = threadIdx.x & 63;
    const long long wavesPerBlock = blockDim.x >> 6;
    long long gwave = (long long)blockIdx.x * wavesPerBlock + (threadIdx.x >> 6);
    const long long nwaves = (long long)gridDim.x * wavesPerBlock;
    for (long long e = gwave; e < N_EDGES; e += nwaves) {
        const int src = ei[e];
        const int dst = ei[N_EDGES + e];
        const float2 xv = *(const float2*)(&x[(long long)src * NF + lane * 2]);
        unsigned* o = outu + (long long)dst * NOUT;
        atomicMax(&o[lane * 2],     mapf(xv.x));
        atomicMax(&o[lane * 2 + 1], mapf(xv.y));
        if (lane < 3) {
            const float d = pos[src * 3 + lane] - pos[dst * 3 + lane];
            atomicMax(&o[NF + lane], mapf(d));
        }
    }
}

__global__ void finalize_kernel(unsigned* __restrict__ buf)
{
    const long long total = (long long)N_NODES * NOUT;
    for (long long i = (long long)blockIdx.x * blockDim.x + threadIdx.x;
         i < total; i += (long long)gridDim.x * blockDim.x) {
        const unsigned u = buf[i];
        ((float*)buf)[i] = (u == 0u) ? 0.0f : unmapf(u);
    }
}

// ---------- launch ----------
extern "C" void kernel_launch(void* const* d_in, const int* in_sizes, int n_in,
                              void* d_out, int out_size, void* d_ws, size_t ws_size,
                              hipStream_t stream)
{
    const float* x   = (const float*)d_in[0];
    const float* pos = (const float*)d_in[1];
    const int*   ei  = (const int*)d_in[2];
    float* out = (float*)d_out;

    // ws: gcount[NB], cstart[NB+1], gcursor[NB], list[N_EDGES]  (~6.42 MB)
    const size_t gcount_off = 0;
    const size_t cstart_off = (gcount_off + (size_t)NB * 4 + 255) & ~(size_t)255;
    const size_t gcur_off   = (cstart_off + (size_t)(NB + 1) * 4 + 255) & ~(size_t)255;
    const size_t list_off   = (gcur_off + (size_t)NB * 4 + 255) & ~(size_t)255;
    const size_t ws_needed  = list_off + (size_t)N_EDGES * 4;

    if (ws_size < ws_needed) {
        unsigned* outu = (unsigned*)d_out;
        hipMemsetAsync(d_out, 0, (size_t)N_NODES * NOUT * sizeof(float), stream);
        edge_scatter_max<<<(N_EDGES + 3) / 4, 256, 0, stream>>>(x, pos, ei, outu);
        const long long total = (long long)N_NODES * NOUT;
        finalize_kernel<<<(int)((total + 255) / 256), 256, 0, stream>>>(outu);
        return;
    }

    int* gcount      = (int*)((char*)d_ws + gcount_off);
    int* cstart      = (int*)((char*)d_ws + cstart_off);
    int* gcursor     = (int*)((char*)d_ws + gcur_off);
    unsigned* list   = (unsigned*)((char*)d_ws + list_off);

    hipMemsetAsync(gcount, 0, (size_t)NB * 4, stream);

    coarse_hist<<<256, 256, 0, stream>>>(ei, gcount);
    coarse_scan<<<1, 64, 0, stream>>>(gcount, cstart, gcursor);
    coarse_scatter<<<(N_EDGES + CHUNK - 1) / CHUNK, 256, 0, stream>>>(ei, gcursor, list);
    half_gather<<<2 * NB, 512, 0, stream>>>(x, pos, list, cstart, out);
}